// Round 1
// baseline (1158.904 us; speedup 1.0000x reference)
//
#include <hip/hip_runtime.h>
#include <hip/hip_bf16.h>
#include <math.h>

// MEFL forward, fp32. Shapes: B=4, D=49, C=512, N=27, C2=256.
// Key restructure: ep_W folded into ARM V (VW = feat @ (ep_W@arm_vW)^T), so the
// per-edge chain is a2[49x49] @ VW[49x512] (10 GFLOP) instead of fe @ ep_W^T (75 GFLOP),
// and fe [4,729,49,512] is never materialized. GEM-BN stats accumulated on the fly.

namespace {

constexpr float SCALE_ = 0.0625f;   // 256^-0.5
constexpr float EPS_   = 1e-5f;

// ---------------- generic tiled GEMM: C[M,N] = A[M,K] @ op(W) + bias ----------------
// TB=1: W is [N,K] row-major (torch Linear weight, op = transpose)
// TB=0: W is [K,N] row-major
template<int TB>
__device__ __forceinline__
void gemm_core(const float* __restrict__ A, const float* __restrict__ W,
               const float* __restrict__ bias, float* __restrict__ C,
               int M, int N, int K)
{
  __shared__ float As[32][68];   // k-major, +4 pad (keeps 16B align, spreads banks)
  __shared__ float Ws[32][68];
  const int tid = threadIdx.x;
  const int n0 = blockIdx.x * 64, m0 = blockIdx.y * 64;
  const int tx = tid & 15, ty = tid >> 4;
  float acc[4][4] = {};
  for (int k0 = 0; k0 < K; k0 += 32) {
#pragma unroll
    for (int p = 0; p < 2; ++p) {
      int idx = tid + p * 256;
      int row = idx >> 3, kq = idx & 7;
      float4 v = make_float4(0.f, 0.f, 0.f, 0.f);
      if (m0 + row < M)
        v = *(const float4*)(A + (long)(m0 + row) * K + k0 + kq * 4);
      As[kq*4+0][row] = v.x; As[kq*4+1][row] = v.y;
      As[kq*4+2][row] = v.z; As[kq*4+3][row] = v.w;
    }
    if (TB) {
#pragma unroll
      for (int p = 0; p < 2; ++p) {
        int idx = tid + p * 256;
        int row = idx >> 3, kq = idx & 7;
        float4 v = *(const float4*)(W + (long)(n0 + row) * K + k0 + kq * 4);
        Ws[kq*4+0][row] = v.x; Ws[kq*4+1][row] = v.y;
        Ws[kq*4+2][row] = v.z; Ws[kq*4+3][row] = v.w;
      }
    } else {
#pragma unroll
      for (int p = 0; p < 2; ++p) {
        int idx = tid + p * 256;
        int row = idx >> 4, nq = idx & 15;
        float4 v = *(const float4*)(W + (long)(k0 + row) * N + n0 + nq * 4);
        *(float4*)&Ws[row][nq*4] = v;
      }
    }
    __syncthreads();
#pragma unroll
    for (int k = 0; k < 32; ++k) {
      float4 a4 = *(const float4*)&As[k][ty*4];
      float4 b4 = *(const float4*)&Ws[k][tx*4];
      float av[4] = {a4.x, a4.y, a4.z, a4.w};
      float bv[4] = {b4.x, b4.y, b4.z, b4.w};
#pragma unroll
      for (int i2 = 0; i2 < 4; ++i2)
#pragma unroll
        for (int j2 = 0; j2 < 4; ++j2)
          acc[i2][j2] = fmaf(av[i2], bv[j2], acc[i2][j2]);
    }
    __syncthreads();
  }
  float4 b4 = make_float4(0.f, 0.f, 0.f, 0.f);
  if (bias) b4 = *(const float4*)(bias + n0 + tx*4);
#pragma unroll
  for (int i2 = 0; i2 < 4; ++i2) {
    int m = m0 + ty*4 + i2;
    if (m < M) {
      float4 o;
      o.x = acc[i2][0] + b4.x; o.y = acc[i2][1] + b4.y;
      o.z = acc[i2][2] + b4.z; o.w = acc[i2][3] + b4.w;
      *(float4*)(C + (long)m * N + n0 + tx*4) = o;
    }
  }
}

template<int TB>
__global__ __launch_bounds__(256)
void gemm_k(const float* __restrict__ A, const float* __restrict__ W,
            const float* __restrict__ bias, float* __restrict__ C,
            int M, int N, int K, long aBS, long wBS, long bBS, long cBS)
{
  int z = blockIdx.z;
  gemm_core<TB>(A + (long)z * aBS, W + (long)z * wBS,
                bias ? bias + (long)z * bBS : nullptr,
                C + (long)z * cBS, M, N, K);
}

// 4 GEMMs sharing one A (the GNN f_v projections)
__global__ __launch_bounds__(256)
void gemm4_k(const float* __restrict__ A,
             const float* W0, const float* W1, const float* W2, const float* W3,
             float* C0, float* C1, float* C2, float* C3, int M, int N, int K)
{
  const float* W; float* C;
  switch (blockIdx.z) {
    case 0:  W = W0; C = C0; break;
    case 1:  W = W1; C = C1; break;
    case 2:  W = W2; C = C2; break;
    default: W = W3; C = C3; break;
  }
  gemm_core<1>(A, W, nullptr, C, M, N, K);
}

// ---------------- node-block BN ----------------
__global__ __launch_bounds__(256)
void nb_stats(const float* __restrict__ H, float* __restrict__ mean, float* __restrict__ rs)
{
  int n = blockIdx.x;
  int c = blockIdx.y * 256 + threadIdx.x;
  const float* p = H + (long)n * 196 * 512 + c;
  float s = 0.f, q = 0.f;
  for (int r = 0; r < 196; ++r) { float v = p[(long)r * 512]; s += v; q = fmaf(v, v, q); }
  float m = s * (1.f / 196.f);
  float var = q * (1.f / 196.f) - m * m;
  mean[n * 512 + c] = m;
  rs[n * 512 + c] = rsqrtf(var + EPS_);
}

__global__ __launch_bounds__(256)
void nb_apply(const float* __restrict__ H, const float* __restrict__ mean,
              const float* __restrict__ rs, const float* __restrict__ bw,
              const float* __restrict__ bb, float* __restrict__ fu, float* __restrict__ fv)
{
  int n = blockIdx.x, b = blockIdx.y;
  int t = threadIdx.x;
#pragma unroll
  for (int cq = 0; cq < 2; ++cq) {
    int c = cq * 256 + t;
    float m = mean[n*512+c], r = rs[n*512+c];
    float w = bw[n*512+c], bias = bb[n*512+c];
    const float* hp = H + ((long)(n*4+b)*49) * 512 + c;
    float* fp = fu + ((long)(n*4+b)*49) * 512 + c;
    float s = 0.f;
    for (int d = 0; d < 49; ++d) {
      float v = hp[(long)d*512];
      float o = fmaxf(fmaf((v - m) * r, w, bias), 0.f);
      fp[(long)d*512] = o;
      s += o;
    }
    fv[((long)b*27+n)*512 + c] = s * (1.f / 49.f);
  }
}

// ---------------- fused attention (FAM: ARM=0, ARM edge-attn: ARM=1) ----------------
// 512 threads. Per block: S = softmax(SCALE * Q[49,256] K^T), then P @ V[49,512].
// ARM=1 additionally accumulates GEM-BN partial sums and writes mean over d only.
template<int ARM>
__global__ __launch_bounds__(512)
void attn_k(const float* __restrict__ Qg, const float* __restrict__ Kg,
            const float* __restrict__ Vg, const float* __restrict__ b2p,
            float* __restrict__ outp, float* __restrict__ parts)
{
  __shared__ float Qs[52][68];        // one 64-wide k-chunk, pad 4
  __shared__ float Ks[52][68];        // XOR-swizzled quads (kq ^ (row&7))
  __shared__ float Ss[49][56];
  __shared__ float VsP2[49 * 68];     // V chunk; aliased as P2[32][68] (sync-separated)
  __shared__ float red[16];
  float (*Vs)[68] = (float(*)[68])VsP2;
  float (*P2)[68] = (float(*)[68])VsP2;

  const int tid = threadIdx.x;
  const int bx = blockIdx.x, b = blockIdx.y;
  int qblk, kblk; long obase;
  if (ARM) {
    int i = bx / 27, j = bx - i * 27;
    qblk = j*4 + b; kblk = i*4 + b;
    obase = ((long)b * 729 + bx) * 512;
  } else {
    qblk = bx*4 + b; kblk = b;
    obase = (long)qblk * 49 * 512;
  }
  const float* qp = Qg + (long)qblk * (49 * 256);
  const float* kp = Kg + (long)kblk * (49 * 256);
  const float* vp = Vg + (long)kblk * (49 * 512);

  const int tx = tid & 15;            // e-quad / c-quad
  const int ty4 = tid >> 4;           // 0..31

  // ---- phase 1: S = SCALE * Q K^T, k chunked by 64 ----
  float sacc[2][4] = {};
  const int d0 = ty4 * 2;
  const int e0 = tx * 4;
  const int eh0 = (e0+0)&7, eh1 = (e0+1)&7, eh2 = (e0+2)&7, eh3 = (e0+3)&7;
  const int er0 = (e0+0) > 51 ? 51 : (e0+0);
  const int er1 = (e0+1) > 51 ? 51 : (e0+1);
  const int er2 = (e0+2) > 51 ? 51 : (e0+2);
  const int er3 = (e0+3) > 51 ? 51 : (e0+3);
  for (int kc = 0; kc < 256; kc += 64) {
    for (int idx = tid; idx < 49 * 16; idx += 512) {
      int row = idx >> 4, kq = idx & 15;
      *(float4*)&Qs[row][kq*4] = *(const float4*)(qp + (long)row*256 + kc + kq*4);
      *(float4*)&Ks[row][(kq ^ (row & 7)) * 4] = *(const float4*)(kp + (long)row*256 + kc + kq*4);
    }
    __syncthreads();
    if (d0 < 49) {
      const float* q0 = &Qs[d0][0];
      const float* q1 = &Qs[d0 + 1][0];
      const float* k0 = &Ks[er0][0];
      const float* k1 = &Ks[er1][0];
      const float* k2 = &Ks[er2][0];
      const float* k3 = &Ks[er3][0];
#pragma unroll 4
      for (int kq = 0; kq < 16; ++kq) {
        float4 a0 = *(const float4*)(q0 + kq*4);
        float4 a1 = *(const float4*)(q1 + kq*4);
        float4 b0 = *(const float4*)(k0 + ((kq ^ eh0) * 4));
        float4 b1 = *(const float4*)(k1 + ((kq ^ eh1) * 4));
        float4 b2 = *(const float4*)(k2 + ((kq ^ eh2) * 4));
        float4 b3 = *(const float4*)(k3 + ((kq ^ eh3) * 4));
        float av0[4] = {a0.x, a0.y, a0.z, a0.w};
        float av1[4] = {a1.x, a1.y, a1.z, a1.w};
        float bv[4][4] = {{b0.x,b0.y,b0.z,b0.w},{b1.x,b1.y,b1.z,b1.w},
                          {b2.x,b2.y,b2.z,b2.w},{b3.x,b3.y,b3.z,b3.w}};
#pragma unroll
        for (int j2 = 0; j2 < 4; ++j2) {
#pragma unroll
          for (int qq = 0; qq < 4; ++qq) {
            sacc[0][j2] = fmaf(av0[qq], bv[j2][qq], sacc[0][j2]);
            sacc[1][j2] = fmaf(av1[qq], bv[j2][qq], sacc[1][j2]);
          }
        }
      }
    }
    __syncthreads();
  }
  if (d0 < 49) {
#pragma unroll
    for (int i2 = 0; i2 < 2; ++i2) {
      int d = d0 + i2;
      if (d < 49) {
#pragma unroll
        for (int j2 = 0; j2 < 4; ++j2) {
          int e = e0 + j2;
          if (e < 49) Ss[d][e] = sacc[i2][j2] * SCALE_;
        }
      }
    }
  }
  __syncthreads();

  // ---- phase 2: row softmax ----
  if (tid < 49) {
    float mx = -1e30f;
    for (int e = 0; e < 49; ++e) mx = fmaxf(mx, Ss[tid][e]);
    float sum = 0.f;
    for (int e = 0; e < 49; ++e) { float ex = __expf(Ss[tid][e] - mx); Ss[tid][e] = ex; sum += ex; }
    float inv = 1.f / sum;
    for (int e = 0; e < 49; ++e) Ss[tid][e] *= inv;
  }
  __syncthreads();

  // ---- phase 3: P @ V (+ bias2 and BN partials for ARM) ----
  float s1 = 0.f, s2 = 0.f;
  const int td = ty4;                  // row group: d = td and td+32
  const bool has2 = (td + 32) < 49;
  for (int cc = 0; cc < 512; cc += 64) {
    for (int idx = tid; idx < 49 * 16; idx += 512) {
      int row = idx >> 4, cq = idx & 15;
      *(float4*)&Vs[row][cq*4] = *(const float4*)(vp + (long)row*512 + cc + cq*4);
    }
    __syncthreads();
    float pa[2][4] = {};
#pragma unroll 7
    for (int e = 0; e < 49; ++e) {
      float4 v4 = *(const float4*)&Vs[e][tx*4];
      float p0 = Ss[td][e];
      float p1 = has2 ? Ss[td + 32][e] : 0.f;
      pa[0][0] = fmaf(p0, v4.x, pa[0][0]); pa[0][1] = fmaf(p0, v4.y, pa[0][1]);
      pa[0][2] = fmaf(p0, v4.z, pa[0][2]); pa[0][3] = fmaf(p0, v4.w, pa[0][3]);
      pa[1][0] = fmaf(p1, v4.x, pa[1][0]); pa[1][1] = fmaf(p1, v4.y, pa[1][1]);
      pa[1][2] = fmaf(p1, v4.z, pa[1][2]); pa[1][3] = fmaf(p1, v4.w, pa[1][3]);
    }
    __syncthreads();   // Vs reads complete (P2 aliases Vs)
    if (ARM) {
      float4 bz4 = *(const float4*)(b2p + cc + tx*4);
      float bza[4] = {bz4.x, bz4.y, bz4.z, bz4.w};
      float pc[4];
#pragma unroll
      for (int j2 = 0; j2 < 4; ++j2) {
        float h0 = pa[0][j2] + bza[j2];
        float sm = h0, sq = h0 * h0;
        if (has2) { float h1 = pa[1][j2] + bza[j2]; sm += h1; sq = fmaf(h1, h1, sq); }
        pc[j2] = sm; s1 += sm; s2 += sq;
      }
      *(float4*)&P2[td][tx*4] = make_float4(pc[0], pc[1], pc[2], pc[3]);
      __syncthreads();
      if (tid < 64) {
        float mh = 0.f;
#pragma unroll
        for (int r = 0; r < 32; ++r) mh += P2[r][tid];
        outp[obase + cc + tid] = mh * (1.f / 49.f);
      }
      __syncthreads();
    } else {
      *(float4*)(outp + obase + (long)td*512 + cc + tx*4) =
          make_float4(pa[0][0], pa[0][1], pa[0][2], pa[0][3]);
      if (has2)
        *(float4*)(outp + obase + (long)(td+32)*512 + cc + tx*4) =
            make_float4(pa[1][0], pa[1][1], pa[1][2], pa[1][3]);
    }
  }
  if (ARM) {
    int lane = tid & 63, wid = tid >> 6;
#pragma unroll
    for (int off = 32; off; off >>= 1) { s1 += __shfl_down(s1, off); s2 += __shfl_down(s2, off); }
    if (lane == 0) { red[wid] = s1; red[8 + wid] = s2; }
    __syncthreads();
    if (tid == 0) {
      float a = 0.f, q = 0.f;
#pragma unroll
      for (int ww = 0; ww < 8; ++ww) { a += red[ww]; q += red[8 + ww]; }
      parts[(((long)b * 729) + bx) * 2 + 0] = a;
      parts[(((long)b * 729) + bx) * 2 + 1] = q;
    }
  }
}

// ---------------- small kernels ----------------
__global__ __launch_bounds__(256)
void bias2_k(const float* __restrict__ epW, const float* __restrict__ vb,
             const float* __restrict__ epb, float* __restrict__ bias2)
{
  int c = blockIdx.x * 256 + threadIdx.x;
  float s = epb[c];
  const float* r = epW + (long)c * 512;
  for (int k = 0; k < 512; ++k) s = fmaf(r[k], vb[k], s);
  bias2[c] = s;
}

__global__ __launch_bounds__(256)
void edge_fin(const float* __restrict__ parts, float* __restrict__ ems)
{
  int e = blockIdx.x * 256 + threadIdx.x;
  if (e < 729) {
    float s = 0.f, q = 0.f;
#pragma unroll
    for (int b = 0; b < 4; ++b) {
      s += parts[((long)b * 729 + e) * 2 + 0];
      q += parts[((long)b * 729 + e) * 2 + 1];
    }
    const float inv = 1.f / 100352.f;   // B*D*C
    float m = s * inv;
    float var = q * inv - m * m;
    ems[e*2]   = m;
    ems[e*2+1] = rsqrtf(var + EPS_);
  }
}

__global__ __launch_bounds__(256)
void fe_init_k(float* __restrict__ fe, const float* __restrict__ ems,
               const float* __restrict__ gw, const float* __restrict__ gb)
{
  long idx4 = (long)blockIdx.x * 256 + threadIdx.x;   // 373248 float4s
  long fidx = idx4 * 4;
  int ij = (int)((fidx >> 9) % 729);
  float m = ems[ij*2], rs = ems[ij*2+1];
  float w = gw[ij], bb = gb[ij];
  float4 v = *(float4*)(fe + fidx);
  v.x = fmaf((v.x - m) * rs, w, bb);
  v.y = fmaf((v.y - m) * rs, w, bb);
  v.z = fmaf((v.z - m) * rs, w, bb);
  v.w = fmaf((v.w - m) * rs, w, bb);
  *(float4*)(fe + fidx) = v;
}

__global__ __launch_bounds__(256)
void gnn_edge_bn(const float* __restrict__ vi, const float* __restrict__ vj,
                 const float* __restrict__ el, const float* __restrict__ wv,
                 const float* __restrict__ bv, float* fe)
{
  int ij = blockIdx.x; int i = ij / 27, j = ij - i * 27;
  int t = threadIdx.x;
  __shared__ float red[18];
  float mv[8]; float s = 0.f, q = 0.f;
#pragma unroll
  for (int p = 0; p < 8; ++p) {
    int idx = p * 256 + t; int b = idx >> 9, c = idx & 511;
    float v = vi[((long)b*27+i)*512 + c] + vj[((long)b*27+j)*512 + c]
            + el[((long)b*729+ij)*512 + c];
    mv[p] = v; s += v; q = fmaf(v, v, q);
  }
  int lane = t & 63, wid = t >> 6;
#pragma unroll
  for (int off = 32; off; off >>= 1) { s += __shfl_down(s, off); q += __shfl_down(q, off); }
  if (lane == 0) { red[wid] = s; red[4 + wid] = q; }
  __syncthreads();
  if (t == 0) {
    float S = red[0]+red[1]+red[2]+red[3], Q = red[4]+red[5]+red[6]+red[7];
    float m = S * (1.f / 2048.f);
    red[16] = m;
    red[17] = rsqrtf(Q * (1.f / 2048.f) - m * m + EPS_);
  }
  __syncthreads();
  float m = red[16], rs = red[17];
  float w = wv[ij], bb = bv[ij];
#pragma unroll
  for (int p = 0; p < 8; ++p) {
    int idx = p * 256 + t; int b = idx >> 9, c = idx & 511;
    long o = ((long)b*729+ij)*512 + c;
    fe[o] += fmaxf(fmaf((mv[p] - m) * rs, w, bb), 0.f);
  }
}

__global__ __launch_bounds__(256)
void gnn_agg(const float* __restrict__ fe, const float* __restrict__ ui,
             const float* __restrict__ uj, float* __restrict__ agg)
{
  int i = blockIdx.x, b = blockIdx.y;
  int t = threadIdx.x;
#pragma unroll
  for (int cq = 0; cq < 2; ++cq) {
    int c = cq * 256 + t;
    float sg[27];
    float mx = -1e30f;
#pragma unroll
    for (int j = 0; j < 27; ++j) {
      float x = fe[((long)b*729 + i*27 + j)*512 + c];
      float sgm = 1.f / (1.f + __expf(-x));
      sg[j] = sgm; mx = fmaxf(mx, sgm);
    }
    float sum = 0.f;
#pragma unroll
    for (int j = 0; j < 27; ++j) { float e2 = __expf(sg[j] - mx); sg[j] = e2; sum += e2; }
    float acc = 0.f;
#pragma unroll
    for (int j = 0; j < 27; ++j)
      acc = fmaf(sg[j], uj[((long)b*27+j)*512 + c], acc);
    agg[((long)b*27+i)*512 + c] = ui[((long)b*27+i)*512 + c] + acc / (sum * 27.f);
  }
}

__global__ __launch_bounds__(256)
void gnn_node_bn(const float* __restrict__ agg, const float* __restrict__ wv,
                 const float* __restrict__ bv, float* fv)
{
  int i = blockIdx.x;
  int t = threadIdx.x;
  __shared__ float red[18];
  float mv[8]; float s = 0.f, q = 0.f;
#pragma unroll
  for (int p = 0; p < 8; ++p) {
    int idx = p * 256 + t; int b = idx >> 9, c = idx & 511;
    float v = agg[((long)b*27+i)*512 + c];
    mv[p] = v; s += v; q = fmaf(v, v, q);
  }
  int lane = t & 63, wid = t >> 6;
#pragma unroll
  for (int off = 32; off; off >>= 1) { s += __shfl_down(s, off); q += __shfl_down(q, off); }
  if (lane == 0) { red[wid] = s; red[4 + wid] = q; }
  __syncthreads();
  if (t == 0) {
    float S = red[0]+red[1]+red[2]+red[3], Q = red[4]+red[5]+red[6]+red[7];
    float m = S * (1.f / 2048.f);
    red[16] = m;
    red[17] = rsqrtf(Q * (1.f / 2048.f) - m * m + EPS_);
  }
  __syncthreads();
  float m = red[16], rs = red[17];
  float w = wv[i], bb = bv[i];
#pragma unroll
  for (int p = 0; p < 8; ++p) {
    int idx = p * 256 + t; int b = idx >> 9, c = idx & 511;
    long o = ((long)b*27+i)*512 + c;
    fv[o] += fmaxf(fmaf((mv[p] - m) * rs, w, bb), 0.f);
  }
}

__constant__ int SUB_IDX_c[14] = {0,0,1,1,2,2,4,4,7,7,8,8,11,11};

__global__ __launch_bounds__(64)
void sc_k(const float* __restrict__ fv, const float* __restrict__ mainsc,
          const float* __restrict__ subsc, float* __restrict__ out)
{
  int o = blockIdx.x, b = blockIdx.y;
  int lane = threadIdx.x;
  int r; const float* ap;
  if (o < 27) { r = o; ap = mainsc + (long)o * 512; }
  else        { int k = o - 27; r = SUB_IDX_c[k]; ap = subsc + (long)k * 512; }
  const float* fp = fv + ((long)b*27 + r) * 512;
  float sff = 0.f, saa = 0.f, sfa = 0.f;
  for (int c = lane; c < 512; c += 64) {
    float f = fp[c];
    float a = fmaxf(ap[c], 0.f);
    sff = fmaf(f, f, sff); saa = fmaf(a, a, saa); sfa = fmaf(f, a, sfa);
  }
#pragma unroll
  for (int off = 32; off; off >>= 1) {
    sff += __shfl_down(sff, off); saa += __shfl_down(saa, off); sfa += __shfl_down(sfa, off);
  }
  if (lane == 0)
    out[b * 41 + o] = sfa / (fmaxf(sqrtf(sff), 1e-12f) * fmaxf(sqrtf(saa), 1e-12f));
}

} // namespace

extern "C" void kernel_launch(void* const* d_in, const int* in_sizes, int n_in,
                              void* d_out, int out_size, void* d_ws, size_t ws_size,
                              hipStream_t stream)
{
  (void)in_sizes; (void)n_in; (void)out_size; (void)ws_size;
  const float* x       = (const float*)d_in[0];
  const float* nb_W    = (const float*)d_in[1];
  const float* nb_b    = (const float*)d_in[2];
  const float* nb_bnw  = (const float*)d_in[3];
  const float* nb_bnb  = (const float*)d_in[4];
  const float* fam_qW  = (const float*)d_in[5];
  const float* fam_qb  = (const float*)d_in[6];
  const float* fam_kW  = (const float*)d_in[7];
  const float* fam_kb  = (const float*)d_in[8];
  const float* fam_vW  = (const float*)d_in[9];
  const float* fam_vb  = (const float*)d_in[10];
  const float* arm_qW  = (const float*)d_in[11];
  const float* arm_qb  = (const float*)d_in[12];
  const float* arm_kW  = (const float*)d_in[13];
  const float* arm_kb  = (const float*)d_in[14];
  const float* arm_vW  = (const float*)d_in[15];
  const float* arm_vb  = (const float*)d_in[16];
  const float* ep_W    = (const float*)d_in[17];
  const float* ep_b    = (const float*)d_in[18];
  const float* gem_bnw = (const float*)d_in[19];
  const float* gem_bnb = (const float*)d_in[20];
  const float* gnn_uW  = (const float*)d_in[21];
  const float* gnn_vW  = (const float*)d_in[22];
  const float* gnn_aW  = (const float*)d_in[23];
  const float* gnn_bW  = (const float*)d_in[24];
  const float* gnn_eW  = (const float*)d_in[25];
  const float* gnn_bnvw = (const float*)d_in[26];
  const float* gnn_bnvb = (const float*)d_in[27];
  const float* gnn_bnew = (const float*)d_in[28];
  const float* gnn_bneb = (const float*)d_in[29];
  const float* main_sc  = (const float*)d_in[30];
  const float* sub_sc   = (const float*)d_in[31];
  float* out = (float*)d_out;

  // workspace carve-up (floats); regions reused where lifetimes allow (~42 MB total)
  float* wsf = (float*)d_ws;
  float* Hnb  = wsf;  wsf += (long)27*196*512;   // node GEMM out; reused as feat
  float* fu   = wsf;  wsf += (long)27*196*512;   // f_u; reused as VW, then el
  float* qb_  = wsf;  wsf += (long)5292*256;     // FAM q; reused as ARM Q
  float* Ka   = wsf;  wsf += (long)5292*256;
  float* fe   = wsf;  wsf += (long)4*729*512;    // meanh -> f_e (in place)
  float* kf   = wsf;  wsf += 196*256;
  float* vf   = wsf;  wsf += 196*512;
  float* nbm  = wsf;  wsf += 27*512;
  float* nbr  = wsf;  wsf += 27*512;
  float* Mpre = wsf;  wsf += 512*512;
  float* bias2= wsf;  wsf += 512;
  float* parts= wsf;  wsf += 4*729*2;
  float* ems  = wsf;  wsf += 1460;               // 729*2 padded to mult of 4
  float* fv   = wsf;  wsf += 108*512;
  float* vi   = wsf;  wsf += 108*512;
  float* vj   = wsf;  wsf += 108*512;
  float* uj   = wsf;  wsf += 108*512;
  float* ui   = wsf;  wsf += 108*512;
  float* agg  = wsf;  wsf += 108*512;
  float* feat = Hnb;
  float* Qa   = qb_;
  float* VW   = fu;
  float* el   = fu;

  // 1) node-block GEMMs: H[n] = x @ nb_W[n]^T + nb_b[n]
  gemm_k<1><<<dim3(8,4,27), 256, 0, stream>>>(x, nb_W, nb_b, Hnb,
      196, 512, 512, 0, (long)512*512, 512, (long)196*512);
  // 2) BN stats per (n,c) over 196 rows
  nb_stats<<<dim3(27,2), 256, 0, stream>>>(Hnb, nbm, nbr);
  // 3) BN+ReLU -> f_u, and token-GAP -> f_v
  nb_apply<<<dim3(27,4), 256, 0, stream>>>(Hnb, nbm, nbr, nb_bnw, nb_bnb, fu, fv);
  // 4-5) FAM k, v
  gemm_k<1><<<dim3(4,4,1), 256, 0, stream>>>(x, fam_kW, fam_kb, kf, 196, 256, 512, 0,0,0,0);
  gemm_k<1><<<dim3(8,4,1), 256, 0, stream>>>(x, fam_vW, fam_vb, vf, 196, 512, 512, 0,0,0,0);
  // 6) FAM q = f_u @ fam_qW^T
  gemm_k<1><<<dim3(4,83,1), 256, 0, stream>>>(fu, fam_qW, fam_qb, qb_, 5292, 256, 512, 0,0,0,0);
  // 7) FAM cross-attention -> feat
  attn_k<0><<<dim3(27,4), 512, 0, stream>>>(qb_, kf, vf, nullptr, feat, nullptr);
  // 8-9) ARM Q, K
  gemm_k<1><<<dim3(4,83,1), 256, 0, stream>>>(feat, arm_qW, arm_qb, Qa, 5292, 256, 512, 0,0,0,0);
  gemm_k<1><<<dim3(4,83,1), 256, 0, stream>>>(feat, arm_kW, arm_kb, Ka, 5292, 256, 512, 0,0,0,0);
  // 10) Mpre = ep_W @ arm_vW  (fold edge-proj into V)
  gemm_k<0><<<dim3(8,8,1), 256, 0, stream>>>(ep_W, arm_vW, nullptr, Mpre, 512, 512, 512, 0,0,0,0);
  // 11) bias2 = ep_W @ arm_vb + ep_b
  bias2_k<<<dim3(2), 256, 0, stream>>>(ep_W, arm_vb, ep_b, bias2);
  // 12) VW = feat @ Mpre^T
  gemm_k<1><<<dim3(8,83,1), 256, 0, stream>>>(feat, Mpre, nullptr, VW, 5292, 512, 512, 0,0,0,0);
  // 13) ARM edge attention -> mean_d(h) into fe, BN partials
  attn_k<1><<<dim3(729,4), 512, 0, stream>>>(Qa, Ka, VW, bias2, fe, parts);
  // 14) per-edge BN stats
  edge_fin<<<dim3(3), 256, 0, stream>>>(parts, ems);
  // 15) f_e = BN(mean_d h) in place
  fe_init_k<<<dim3(1458), 256, 0, stream>>>(fe, ems, gem_bnw, gem_bnb);
  // 16) 2 GatedGNN layers
  for (int l = 0; l < 2; ++l) {
    long wo = (long)l * 512 * 512;
    gemm4_k<<<dim3(8,2,4), 256, 0, stream>>>(fv,
        gnn_aW + wo, gnn_bW + wo, gnn_vW + wo, gnn_uW + wo,
        vi, vj, uj, ui, 108, 512, 512);
    gemm_k<1><<<dim3(8,46,1), 256, 0, stream>>>(fe, gnn_eW + wo, nullptr, el,
        2916, 512, 512, 0,0,0,0);
    gnn_edge_bn<<<dim3(729), 256, 0, stream>>>(vi, vj, el,
        gnn_bnew + (long)l*729, gnn_bneb + (long)l*729, fe);
    gnn_agg<<<dim3(27,4), 256, 0, stream>>>(fe, ui, uj, agg);
    gnn_node_bn<<<dim3(27), 256, 0, stream>>>(agg,
        gnn_bnvw + (long)l*27, gnn_bnvb + (long)l*27, fv);
  }
  // 17) cosine-similarity outputs [4,41]
  sc_k<<<dim3(41,4), 64, 0, stream>>>(fv, main_sc, sub_sc, out);
}